// Round 13
// baseline (611.549 us; speedup 1.0000x reference)
//
#include <hip/hip_runtime.h>
#include <hip/hip_bf16.h>

typedef __attribute__((ext_vector_type(8))) short bf16x8;
typedef __attribute__((ext_vector_type(16))) float f32x16;

#define GLDS(g, l) \
  __builtin_amdgcn_global_load_lds((const __attribute__((address_space(1))) void*)(g), \
                                   (__attribute__((address_space(3))) void*)(l), 16, 0, 0)

#define MFMA32 __builtin_amdgcn_mfma_f32_32x32x16_bf16

// ---------------- Kernel 1: X fp32 -> bf16 (r8-proven) ----------------
__global__ __launch_bounds__(256) void k_cvt_bf16(const float* __restrict__ x,
                                                  __hip_bfloat16* __restrict__ y,
                                                  long n8) {
  long stride = (long)gridDim.x * blockDim.x;
  for (long i = (long)blockIdx.x * blockDim.x + threadIdx.x; i < n8; i += stride) {
    const float4* xin = reinterpret_cast<const float4*>(x) + i * 2;
    float4 v0 = xin[0];
    float4 v1 = xin[1];
    union { __hip_bfloat16 h[8]; int4 v; } o;
    o.h[0] = __float2bfloat16(v0.x);
    o.h[1] = __float2bfloat16(v0.y);
    o.h[2] = __float2bfloat16(v0.z);
    o.h[3] = __float2bfloat16(v0.w);
    o.h[4] = __float2bfloat16(v1.x);
    o.h[5] = __float2bfloat16(v1.y);
    o.h[6] = __float2bfloat16(v1.z);
    o.h[7] = __float2bfloat16(v1.w);
    *reinterpret_cast<int4*>(y + i * 8) = o.v;
  }
}

// ---------------- Kernel 2: assemble W bf16 (r8-proven, low-traffic) ----------------
__global__ __launch_bounds__(256) void k_make_w(const float* __restrict__ L,
                                                const float* __restrict__ R,
                                                __hip_bfloat16* __restrict__ W) {
  const int bc = blockIdx.x;  // b*64 + c
  const int b = bc >> 6, c = bc & 63;
  const int d = threadIdx.x & 63;
  const int q = threadIdx.x >> 6;
  float Rr[8];
#pragma unroll
  for (int r = 0; r < 8; ++r)
    Rr[r] = R[(((size_t)(r * 64 + b) * 64 + c) << 6) + d];
#pragma unroll 4
  for (int a = q * 16; a < q * 16 + 16; ++a) {
    const float* Lp = L + (((size_t)(a * 64 + b) * 64 + c) << 3);
    float s = 0.f;
#pragma unroll
    for (int r = 0; r < 8; ++r) s = fmaf(Lp[r], Rr[r], s);
    W[((size_t)(a * 64 + b) << 12) + (c << 6) + d] = __float2bfloat16(s);
  }
}

// ---------------- Kernel 3: 256x256 bf16 GEMM — 32x32x16 MFMA on the r12 skeleton ----
// Sync: r12's proven tile boundary (explicit pre-barrier lgkm0+vmcnt0 drain; the
// r5/r6/r11 race lessons). Phases fence-free (compiler-tracked ds_read->MFMA deps).
// Per wave: 4 mt (32-row) x 2 nt (32-col) tiles, acc = f32x16[4][2] (128 AGPR).
// Per phase: 8 MFMA (2 mt x 4 kt). Swizzle read-balance verified: 8 lanes per 16B
// position -> conflict-free wave64 b128.
__global__ __launch_bounds__(512, 2) void k_gemm_bt(const __hip_bfloat16* __restrict__ A,
                                                    const __hip_bfloat16* __restrict__ B,
                                                    const float* __restrict__ bias,
                                                    float* __restrict__ C) {
  const int K = 4096, N = 4096, NT = 64;
  __shared__ char lds[131072];
  char* const sAc = lds;          // 2 x 32768: A tile [256][64] bf16, swizzled
  char* const sBc = lds + 65536;  // 2 x 32768

  const int tid = threadIdx.x;
  const int lane = tid & 63;
  const int wid = tid >> 6;
  const int wr = wid >> 2;    // 0..1 (M half: 128 rows)
  const int wc = wid & 3;     // 0..3 (N quarter: 64 cols)

  // T1: bijective XCD swizzle (nwg = 1024, divisible by 8)
  const int orig = blockIdx.x;
  const int wg = (orig & 7) * 128 + (orig >> 3);
  const int gm0 = (wg >> 4) * 256;
  const int gn0 = (wg & 15) * 256;

  // ---- staging geometry (pre-swizzled global source, linear LDS dest; r8/r12) ----
  const int crow = tid >> 3;
  const int scol = ((tid & 7) << 4) ^ ((crow & 7) << 4);
  const int voff = crow * 8192 + scol;
  const int wbase = (tid >> 6) << 10;
  const char* const Ab = (const char*)(A + (size_t)gm0 * K);
  const char* const Bb = (const char*)(B + (size_t)gn0 * K);

#define STAGEA(BUF, TS)                                                      \
  _Pragma("unroll")                                                          \
  for (int j = 0; j < 4; ++j)                                                \
    GLDS(Ab + (size_t)((TS) * 128 + j * 524288) + voff,                      \
         sAc + (BUF) * 32768 + j * 8192 + wbase);

#define STAGEB(BUF, TS)                                                      \
  _Pragma("unroll")                                                          \
  for (int j = 0; j < 4; ++j)                                                \
    GLDS(Bb + (size_t)((TS) * 128 + j * 524288) + voff,                      \
         sBc + (BUF) * 32768 + j * 8192 + wbase);

  // ---- fragment-read geometry (swizzled ds_read, 32x32x16) ----
  // A-frag(mt,kt): lane reads A[row = wr*128 + mt*32 + (lane&31)]
  //                          [k = kt*16 + (lane>>5)*8 + e], e=0..7 (16B)
  const int lane31 = lane & 31;
  const int swz = (lane31 & 7) << 4;
  const int lh16 = (lane >> 5) << 4;
  int xc[4];
#pragma unroll
  for (int kt = 0; kt < 4; ++kt) xc[kt] = ((kt << 5) + lh16) ^ swz;
  const char* const rA = sAc + (((wr << 7) + lane31) << 7);
  const char* const rB = sBc + (((wc << 6) + lane31) << 7);

#define PREFA32(DST, BUF, MT0)                                               \
  _Pragma("unroll")                                                          \
  for (int mt = 0; mt < 2; ++mt)                                             \
    _Pragma("unroll")                                                        \
    for (int kt = 0; kt < 4; ++kt)                                           \
      DST[mt][kt] = *(const bf16x8*)(rA + (BUF) * 32768 + ((MT0) + mt) * 4096 + xc[kt]);

#define PREFB32(DST, BUF, NT0)                                               \
  _Pragma("unroll")                                                          \
  for (int kt = 0; kt < 4; ++kt)                                             \
    DST[kt] = *(const bf16x8*)(rB + (BUF) * 32768 + (NT0) * 4096 + xc[kt]);

#define MFMA8(AF, BF, MB, NB)                                                \
  _Pragma("unroll")                                                          \
  for (int kt = 0; kt < 4; ++kt)                                             \
    _Pragma("unroll")                                                        \
    for (int mt = 0; mt < 2; ++mt)                                           \
      acc[(MB) + mt][NB] = MFMA32(AF[mt][kt], BF[kt], acc[(MB) + mt][NB], 0, 0, 0);

#define SBAR0 __builtin_amdgcn_sched_barrier(0)
// Tile boundary (r12-proven): per-wave drain of ALL lds + ALL vmem (incl
// global_load_lds) BEFORE s_barrier; sched_barrier brackets pin placement.
#define TILE_SYNC                                                            \
  asm volatile("s_waitcnt lgkmcnt(0) vmcnt(0)" ::: "memory");                \
  SBAR0;                                                                     \
  __builtin_amdgcn_s_barrier();                                              \
  SBAR0;

  // epilogue coords; 32x32 C/D layout (m74/m101): col = lane&31,
  // row = (reg&3) + 8*(reg>>2) + 4*(lane>>5)
  const int er = gm0 + (wr << 7) + ((lane >> 5) << 2);
  const int ec = gn0 + (wc << 6) + lane31;

  f32x16 acc[4][2];
#pragma unroll
  for (int nt = 0; nt < 2; ++nt) {
    const float bv = bias[ec + nt * 32];
#pragma unroll
    for (int mt = 0; mt < 4; ++mt)
#pragma unroll
      for (int j = 0; j < 16; ++j) acc[mt][nt][j] = bv;
  }

  bf16x8 aX[2][4], aY[2][4], b0[4], b2[4];

  // ---- prologue: stage tiles 0,1; explicit drain of tile 0; publish; first reads ----
  STAGEA(0, 0) STAGEB(0, 0) STAGEA(1, 1) STAGEB(1, 1)
  asm volatile("s_waitcnt vmcnt(8)" ::: "memory");
  SBAR0;
  __builtin_amdgcn_s_barrier();
  SBAR0;
  PREFA32(aX, 0, 0) PREFB32(b0, 0, 0)

  // Phases: P1(mt01,nt0,aX) P2(mt23,nt0,aY) P3(mt01,nt1,aX) P4(mt23,nt1,aY)
  // Prefetch: P1->aY=A-mt23(t)  P2->b2=B-nt1(t)  P3->b0=B-nt0(t+1)  P4->aX=A-mt01(t+1)
  // Staging:  P3: A(t+2)->BUF (post-sync);  P4: B(t+2)->BUF
#define TILE(BUF, T)                                                         \
  {                                                                          \
    const int tS = ((T) + 2 < NT) ? (T) + 2 : NT - 1;                        \
    /* P1 */                                                                 \
    PREFA32(aY, BUF, 2)                                                      \
    __builtin_amdgcn_s_setprio(1);                                           \
    MFMA8(aX, b0, 0, 0)                                                      \
    __builtin_amdgcn_s_setprio(0);                                           \
    /* P2 */                                                                 \
    PREFB32(b2, BUF, 1)                                                      \
    __builtin_amdgcn_s_setprio(1);                                           \
    MFMA8(aY, b0, 2, 0)                                                      \
    __builtin_amdgcn_s_setprio(0);                                           \
    /* P3: tile boundary (explicit certify-then-publish) */                  \
    TILE_SYNC                                                                \
    STAGEA(BUF, tS)                                                          \
    PREFB32(b0, (BUF) ^ 1, 0)                                                \
    __builtin_amdgcn_s_setprio(1);                                           \
    MFMA8(aX, b2, 0, 1)                                                      \
    __builtin_amdgcn_s_setprio(0);                                           \
    /* P4 */                                                                 \
    STAGEB(BUF, tS)                                                          \
    PREFA32(aX, (BUF) ^ 1, 0)                                                \
    __builtin_amdgcn_s_setprio(1);                                           \
    MFMA8(aY, b2, 2, 1)                                                      \
    __builtin_amdgcn_s_setprio(0);                                           \
  }

  for (int t = 0; t < NT; t += 2) {
    TILE(0, t)
    TILE(1, t + 1)
  }
  asm volatile("s_waitcnt vmcnt(0) lgkmcnt(0)" ::: "memory");

  // ---- epilogue: C[row][col] = acc (bias pre-seeded) ----
#pragma unroll
  for (int nt = 0; nt < 2; ++nt) {
    const int c = ec + nt * 32;
#pragma unroll
    for (int mt = 0; mt < 4; ++mt) {
      const int r0 = er + mt * 32;
#pragma unroll
      for (int r = 0; r < 16; ++r) {
        const int row = r0 + (r & 3) + ((r >> 2) << 3);
        C[(size_t)row * N + c] = acc[mt][nt][r];
      }
    }
  }
}

extern "C" void kernel_launch(void* const* d_in, const int* in_sizes, int n_in,
                              void* d_out, int out_size, void* d_ws, size_t ws_size,
                              hipStream_t stream) {
  const float* x = (const float*)d_in[0];     // [8,2048,4096]
  const float* L = (const float*)d_in[1];     // [64,64,64,8]
  const float* R = (const float*)d_in[2];     // [8,64,64,64]
  const float* bias = (const float*)d_in[3];  // [4096]
  float* out = (float*)d_out;                 // [16384,4096]

  __hip_bfloat16* Wb = (__hip_bfloat16*)d_ws;                                    // 33.5 MB
  __hip_bfloat16* Xb = (__hip_bfloat16*)((char*)d_ws + (size_t)4096 * 4096 * 2); // 134 MB

  const long n8 = (long)16384 * 4096 / 8;
  k_cvt_bf16<<<4096, 256, 0, stream>>>(x, Xb, n8);
  k_make_w<<<4096, 256, 0, stream>>>(L, R, Wb);

  dim3 grid(1024);  // (16384/256) * (4096/256)
  k_gemm_bt<<<grid, 512, 0, stream>>>(Xb, Wb, bias, out);
}